// Round 14
// baseline (716.218 us; speedup 1.0000x reference)
//
#include <hip/hip_runtime.h>

// LSTM predictor: B=1024, T=1024, H=51, input=1. Sequential recurrence.
//
// Round 14 = round 12 duo structure with v_fma_mix_f32 weights.
// Allocator law (rounds 1-13): barriered-loop arch-VGPR grant ceiling is
// ~88 (duo) / ~52 (4-wave); demand above it goes to AGPR with an
// accvgpr_read per use. fp32 weights (104/wave) never fit. v_fma_mix_f32
// solves it: f16-PACKED weight storage (52 regs for 2 gates) consumed at
// FULL fp32 FMA rate with fp32 h (no f16-h quantization, no dot2
// half-rate). Numerics: f16 weights + fp32 h is strictly better than
// round 6's passing config (f16 both).
//
//  - 2 waves/block, block=batch. wave0: gates i,f; wave1: g,o.
//  - 26 packed f16-pair weight regs per gate (52/wave), asm fma_mix use.
//  - h broadcast: per-wave fp32 LDS replica, 13 uniform ds_read_b128.
//  - Activation exchange: parity double-buffered LDS + ONE barrier;
//    redundant bit-identical c/h update on both waves.
//  - fc output staged by wave0 in stride-65 LDS, reduced every 64 steps.

#define HID 51
#define SEQ_T 1024
#define NPAIR 26  // k-pairs per gate (k=51 padded with zero weight)

typedef _Float16 f16;
typedef unsigned int u32;
typedef __attribute__((ext_vector_type(2))) _Float16 half2_t;

static __device__ __forceinline__ float lane_bcast(float v, int lane) {
    return __int_as_float(__builtin_amdgcn_readlane(__float_as_int(v), lane));
}
static __device__ __forceinline__ float fast_sigmoid(float x) {
    float e = __builtin_amdgcn_exp2f(x * -1.44269504088896340736f);
    return __builtin_amdgcn_rcpf(1.0f + e);
}
static __device__ __forceinline__ float fast_tanh(float x) {
    float e = __builtin_amdgcn_exp2f(x * 2.88539008177792681472f);
    return 1.0f - 2.0f * __builtin_amdgcn_rcpf(e + 1.0f);
}

// acc(f32) += f16(lo/hi of wp) * h(f32); full-rate FMA with operand cast.
#define MIX_LO(acc, wp, hf) \
    asm("v_fma_mix_f32 %0, %1, %2, %0 op_sel_hi:[1,0,0]" \
        : "+v"(acc) : "v"(wp), "v"(hf))
#define MIX_HI(acc, wp, hf) \
    asm("v_fma_mix_f32 %0, %1, %2, %0 op_sel:[1,0,0] op_sel_hi:[1,0,0]" \
        : "+v"(acc) : "v"(wp), "v"(hf))

__global__ __launch_bounds__(128)
__attribute__((amdgpu_waves_per_eu(2, 2)))
void lstm_mix_kernel(
    const float* __restrict__ x,      // [B, T]
    const float* __restrict__ W_ih,   // [4H, 1]
    const float* __restrict__ W_hh,   // [4H, H]
    const float* __restrict__ b_ih,   // [4H]
    const float* __restrict__ b_hh,   // [4H]
    const float* __restrict__ fc_w,   // [1, H]
    const float* __restrict__ fc_b,   // [1]
    float* __restrict__ out)          // [B, T]
{
    const int b = blockIdx.x;
    const int tid = threadIdx.x;
    const int w = tid >> 6;  // 0: gates {i,f}; 1: gates {g,o}
    const int l = tid & 63;
    const bool act = (l < HID);

    __shared__ __align__(16) float hrep[2][64];  // per-wave fp32 h replica
    __shared__ float2 axch[2][2][64];            // [parity][wave][lane]
    __shared__ float pbuf[64][65];               // fc staging (wave0 only)

    const int gA = 2 * w;      // wave0: i, wave1: g
    const int gB = 2 * w + 1;  // wave0: f, wave1: o

    // ---- per-lane weights: 2 gate-rows as f16 pairs = 52 VGPRs ----
    u32 wpA[NPAIR], wpB[NPAIR];
#pragma unroll
    for (int p = 0; p < NPAIR; ++p) {
        float a0 = 0.f, a1 = 0.f, c0 = 0.f, c1 = 0.f;
        if (act) {
            const int k0 = 2 * p, k1 = 2 * p + 1;
            a0 = W_hh[(gA * HID + l) * HID + k0];
            c0 = W_hh[(gB * HID + l) * HID + k0];
            if (k1 < HID) {
                a1 = W_hh[(gA * HID + l) * HID + k1];
                c1 = W_hh[(gB * HID + l) * HID + k1];
            }
        }
        half2_t pa = { (f16)a0, (f16)a1 };
        half2_t pc = { (f16)c0, (f16)c1 };
        wpA[p] = __builtin_bit_cast(u32, pa);
        wpB[p] = __builtin_bit_cast(u32, pc);
        asm volatile("" : "+v"(wpA[p]), "+v"(wpB[p]));
    }
    float bA = 0.f, bB = 0.f, wxA = 0.f, wxB = 0.f, fcw = 0.f;
    if (act) {
        bA = b_ih[gA * HID + l] + b_hh[gA * HID + l];
        bB = b_ih[gB * HID + l] + b_hh[gB * HID + l];
        wxA = W_ih[gA * HID + l];
        wxB = W_ih[gB * HID + l];
        fcw = fc_w[l];
    }
    const float fcb = fc_b[0];
    float c = 0.f;

    hrep[w][l] = 0.f;  // own replica; same-wave write->read via lgkm order
    __syncthreads();

    const float4* __restrict__ hq4 = (const float4*)(&hrep[w][0]);

#pragma unroll 1
    for (int t0 = 0; t0 < SEQ_T; t0 += 64) {
        const float xv = x[b * SEQ_T + t0 + l];  // 64 steps of input

#pragma unroll 1
        for (int i = 0; i < 64; ++i) {
            const float xt = lane_bcast(xv, i);
            // 4 accumulator chains (A0,B0,A1,B1): same-chain gap 8 cyc.
            float sA0 = fmaf(xt, wxA, bA), sA1 = 0.f;
            float sB0 = fmaf(xt, wxB, bB), sB1 = 0.f;
#pragma unroll
            for (int q = 0; q < 13; ++q) {
                const float4 h4 = hq4[q];  // uniform addr -> broadcast read
                MIX_LO(sA0, wpA[2 * q + 0], h4.x);
                MIX_LO(sB0, wpB[2 * q + 0], h4.x);
                MIX_HI(sA1, wpA[2 * q + 0], h4.y);
                MIX_HI(sB1, wpB[2 * q + 0], h4.y);
                MIX_LO(sA0, wpA[2 * q + 1], h4.z);
                MIX_LO(sB0, wpB[2 * q + 1], h4.z);
                MIX_HI(sA1, wpA[2 * q + 1], h4.w);
                MIX_HI(sB1, wpB[2 * q + 1], h4.w);
            }
            const float sA = sA0 + sA1;
            const float sB = sB0 + sB1;

            // ---- activations (wave-uniform branch) + exchange ----
            float aA, aB;
            if (w == 0) { aA = fast_sigmoid(sA); aB = fast_sigmoid(sB); }
            else        { aA = fast_tanh(sA);    aB = fast_sigmoid(sB); }
            const int par = i & 1;
            axch[par][w][l] = make_float2(aA, aB);
            __syncthreads();  // the ONE barrier per step
            const float2 oth = axch[par][1 - w][l];

            float ig, fg, gg, og;
            if (w == 0) { ig = aA;    fg = aB;    gg = oth.x; og = oth.y; }
            else        { ig = oth.x; fg = oth.y; gg = aA;    og = aB; }

            // ---- redundant fp32 c/h update (bit-identical across waves) --
            c = fmaf(fg, c, ig * gg);
            const float hn = og * fast_tanh(c);
            // pad lanes: zero params -> s=0 -> g=0 -> c=0 -> hn=0.
            hrep[w][l] = hn;

            if (w == 0) pbuf[l][i] = hn * fcw;  // fc staging
        }

        if (w == 0) {
            float s2r = 0.f;
#pragma unroll
            for (int k = 0; k < HID; ++k) s2r += pbuf[k][l];
            out[b * SEQ_T + t0 + l] = s2r + fcb;  // coalesced 64-chunk
        }
    }
}

extern "C" void kernel_launch(void* const* d_in, const int* in_sizes, int n_in,
                              void* d_out, int out_size, void* d_ws, size_t ws_size,
                              hipStream_t stream) {
    (void)in_sizes; (void)n_in; (void)d_ws; (void)ws_size; (void)out_size;
    const float* x    = (const float*)d_in[0];
    const float* W_ih = (const float*)d_in[1];
    const float* W_hh = (const float*)d_in[2];
    const float* b_ih = (const float*)d_in[3];
    const float* b_hh = (const float*)d_in[4];
    const float* fc_w = (const float*)d_in[5];
    const float* fc_b = (const float*)d_in[6];
    float* out = (float*)d_out;

    lstm_mix_kernel<<<dim3(1024), dim3(128), 0, stream>>>(
        x, W_ih, W_hh, b_ih, b_hh, fc_w, fc_b, out);
}